// Round 11
// baseline (385.852 us; speedup 1.0000x reference)
//
#include <hip/hip_runtime.h>
#include <hip/hip_bf16.h>
#include <math.h>

#define T_TOK   131072
#define D_IN    2048
#define H_CH    260
#define NF32    9                          // 9 frags x 32 cols = 288 padded N
#define KS16    128                        // 2048 / 16
#define STEP16_BYTES (NF32 * 64 * 16)      // 9216 B per K16-step
#define CHUNK_STEPS  4                     // K = 64 per chunk
#define CHUNK_BYTES  (CHUNK_STEPS * STEP16_BYTES)   // 36864 B
#define NCHUNK  (KS16 / CHUNK_STEPS)       // 32

typedef __attribute__((ext_vector_type(8)))  short bf16x8;
typedef __attribute__((ext_vector_type(4)))  float f32x4;
typedef __attribute__((ext_vector_type(16))) float f32x16;

__device__ inline short f2bf(float x) {
    __hip_bfloat16 h = __float2bfloat16(x);
    return __builtin_bit_cast(short, h);
}

__device__ inline void glds16(const void* src, void* lds_dst) {
    __builtin_amdgcn_global_load_lds(
        (const __attribute__((address_space(1))) unsigned int*)src,
        (__attribute__((address_space(3))) unsigned int*)lds_dst, 16, 0, 0);
}

// ---------------------------------------------------------------------------
// Prep: pack W_down [2048,260] fp32 -> 32x32x16-MFMA B-fragment bf16 layout.
// Frag (s,f): Wf[(s*NF32+f)*64 + lane][j] = W[s*16 + (lane>>5)*8 + j][f*32 + (lane&31)]
// ---------------------------------------------------------------------------
__global__ void prep_wfrag(const float* __restrict__ W, __hip_bfloat16* __restrict__ Wf) {
    int g = blockIdx.x;                 // 0 .. KS16*NF32-1
    int s = g / NF32, f = g % NF32;
    int lane = threadIdx.x;
    int k0 = s * 16 + (lane >> 5) * 8;
    int col = f * 32 + (lane & 31);
    short vals8[8];
#pragma unroll
    for (int j = 0; j < 8; j++) {
        float v = (col < H_CH) ? W[(size_t)(k0 + j) * H_CH + col] : 0.f;
        vals8[j] = f2bf(v);
    }
    *reinterpret_cast<bf16x8*>(reinterpret_cast<short*>(Wf) + ((size_t)g * 64 + lane) * 8) =
        *reinterpret_cast<bf16x8*>(vals8);
}

// ---------------------------------------------------------------------------
// Main GEMM with 32x32x16 MFMA. Block = 256 threads (4 waves), 128 rows.
// Wave w: rows blk*128 + w*32 .. +31 (unique -> A read once from HBM to regs).
// Full N=288 per wave: 9 accs of f32x16 (144 VGPR). LDS stages B only:
// chunk = 4 K16-steps = 36 KB, double-buffered (72 KB) -> 2 blocks/CU.
// Counted-vmcnt barrier: drain B-glds, carry next-chunk A loads in flight.
// ---------------------------------------------------------------------------
__global__ __launch_bounds__(256, 2)
void gemm_act(const float* __restrict__ emb, const __hip_bfloat16* __restrict__ Wfrag,
              const float* __restrict__ b_down, const float* __restrict__ W_final,
              const float* __restrict__ b_final,
              float* __restrict__ attnL, __hip_bfloat16* __restrict__ vals,
              float* __restrict__ token_logits) {
    __shared__ __align__(16) char smem[2 * CHUNK_BYTES];   // 72 KB

    int wave = threadIdx.x >> 6;
    int lane = threadIdx.x & 63;
    int r0 = blockIdx.x * 128 + wave * 32;
    int row_in = lane & 31;
    int kbase = (lane >> 5) * 8;
    int hi = lane >> 5;

    const char* gW = (const char*)Wfrag;

    // 36 x 1024B segments per chunk; 4 waves x 9 segments each.
    auto stage_chunk = [&](int c, char* lbase) {
        const char* src = gW + (size_t)c * CHUNK_BYTES;
#pragma unroll
        for (int r = 0; r < 9; ++r) {
            int off = (r * 4 + wave) * 1024;
            glds16(src + off + lane * 16, lbase + off);
        }
    };

    f32x16 acc[NF32];
#pragma unroll
    for (int f = 0; f < NF32; f++)
#pragma unroll
        for (int i = 0; i < 16; i++) acc[f][i] = 0.f;

    const float* aptr = emb + (size_t)(r0 + row_in) * D_IN + kbase;

    f32x4 P0, P1, P2, P3, P4, P5, P6, P7;   // A for current chunk (4 steps x 8 floats)
    f32x4 Q0, Q1, Q2, Q3, Q4, Q5, Q6, Q7;   // A for next chunk

#define LOAD_A8(R, boff)                                          \
    R##0 = *reinterpret_cast<const f32x4*>(aptr + (boff));        \
    R##1 = *reinterpret_cast<const f32x4*>(aptr + (boff) + 4);    \
    R##2 = *reinterpret_cast<const f32x4*>(aptr + (boff) + 16);   \
    R##3 = *reinterpret_cast<const f32x4*>(aptr + (boff) + 20);   \
    R##4 = *reinterpret_cast<const f32x4*>(aptr + (boff) + 32);   \
    R##5 = *reinterpret_cast<const f32x4*>(aptr + (boff) + 36);   \
    R##6 = *reinterpret_cast<const f32x4*>(aptr + (boff) + 48);   \
    R##7 = *reinterpret_cast<const f32x4*>(aptr + (boff) + 52);

#define DO_STEP16(AL, AH, BOFF)                                                   \
    {                                                                             \
        bf16x8 af;                                                                \
        af[0] = f2bf(AL[0]); af[1] = f2bf(AL[1]);                                 \
        af[2] = f2bf(AL[2]); af[3] = f2bf(AL[3]);                                 \
        af[4] = f2bf(AH[0]); af[5] = f2bf(AH[1]);                                 \
        af[6] = f2bf(AH[2]); af[7] = f2bf(AH[3]);                                 \
        const char* bb = smem + (BOFF) + lane * 16;                               \
        _Pragma("unroll")                                                         \
        for (int f = 0; f < NF32; f++) {                                          \
            bf16x8 bfr = *reinterpret_cast<const bf16x8*>(bb + f * 1024);         \
            acc[f] = __builtin_amdgcn_mfma_f32_32x32x16_bf16(af, bfr, acc[f], 0, 0, 0); \
        }                                                                         \
    }

#define DO_CHUNK(R, base)                                   \
    DO_STEP16(R##0, R##1, (base));                          \
    DO_STEP16(R##2, R##3, (base) + STEP16_BYTES);           \
    DO_STEP16(R##4, R##5, (base) + 2 * STEP16_BYTES);       \
    DO_STEP16(R##6, R##7, (base) + 3 * STEP16_BYTES);

    // prologue: stage B(0), load A(chunk 0), full drain once
    stage_chunk(0, smem);
    LOAD_A8(P, 0)
    __syncthreads();

    for (int c = 0; c < NCHUNK; ++c) {
        int base = (c & 1) * CHUNK_BYTES;

        // 1) stage B(c+1) (oldest 9 in vmem queue)
        if (c + 1 < NCHUNK) stage_chunk(c + 1, smem + ((c + 1) & 1) * CHUNK_BYTES);
        __builtin_amdgcn_sched_barrier(0);

        // 2) load A(c+1) (newest 8; ride across the barrier)
        int aoff = ((c + 1 < NCHUNK) ? (c + 1) * 64 : 0);
        LOAD_A8(Q, aoff)
        __builtin_amdgcn_sched_barrier(0);

        // 3) compute chunk c: 4 x (9 ds_read + 9 MFMA)
        DO_CHUNK(P, base)

        // 4) drain the 9 B-glds (L2-fast); keep the 8 A loads in flight
        asm volatile("s_waitcnt vmcnt(8) lgkmcnt(0)" ::: "memory");
        __builtin_amdgcn_s_barrier();

        P0 = Q0; P1 = Q1; P2 = Q2; P3 = Q3;
        P4 = Q4; P5 = Q5; P6 = Q6; P7 = Q7;
    }
#undef DO_CHUNK
#undef DO_STEP16
#undef LOAD_A8

    // Epilogue. C/D layout: col = lane&31, row = (r&3) + 8*(r>>2) + 4*hi.
    int colbase = lane & 31;
    float tp0, tp1, tp2, tp3, tp4, tp5, tp6, tp7;
    float tp8, tp9, tp10, tp11, tp12, tp13, tp14, tp15;
    tp0=tp1=tp2=tp3=tp4=tp5=tp6=tp7=0.f;
    tp8=tp9=tp10=tp11=tp12=tp13=tp14=tp15=0.f;
#pragma unroll
    for (int f = 0; f < NF32; f++) {
        int n = f * 32 + colbase;
        float bias = (n < H_CH) ? b_down[n] : 0.f;
        float wf = (n >= 4 && n < H_CH) ? W_final[n - 4] : 0.f;
#pragma unroll
        for (int r = 0; r < 16; r++) {
            int row = r0 + (r & 3) + 8 * (r >> 2) + 4 * hi;
            float v = acc[f][r] + bias;
            float a = (n < 4) ? v : 0.5f * v * (1.f + erff(v * 0.70710678118f));
            if (n < 4) {
                attnL[(size_t)row * 4 + n] = v;
            } else if (n < H_CH) {
                vals[(size_t)row * 256 + (n - 4)] = __float2bfloat16(a);
            }
            float contrib = a * wf;
            switch (r) {
                case 0: tp0 += contrib; break;   case 1: tp1 += contrib; break;
                case 2: tp2 += contrib; break;   case 3: tp3 += contrib; break;
                case 4: tp4 += contrib; break;   case 5: tp5 += contrib; break;
                case 6: tp6 += contrib; break;   case 7: tp7 += contrib; break;
                case 8: tp8 += contrib; break;   case 9: tp9 += contrib; break;
                case 10: tp10 += contrib; break; case 11: tp11 += contrib; break;
                case 12: tp12 += contrib; break; case 13: tp13 += contrib; break;
                case 14: tp14 += contrib; break; case 15: tp15 += contrib; break;
            }
        }
    }
#define TOK_REDUCE(r, v)                                                      \
    {                                                                         \
        float x_ = (v);                                                       \
        x_ += __shfl_xor(x_, 1);  x_ += __shfl_xor(x_, 2);                    \
        x_ += __shfl_xor(x_, 4);  x_ += __shfl_xor(x_, 8);                    \
        x_ += __shfl_xor(x_, 16);                                             \
        if ((lane & 31) == 0)                                                 \
            token_logits[r0 + ((r) & 3) + 8 * ((r) >> 2) + 4 * hi] = x_ + b_final[0]; \
    }
    TOK_REDUCE(0, tp0)   TOK_REDUCE(1, tp1)   TOK_REDUCE(2, tp2)   TOK_REDUCE(3, tp3)
    TOK_REDUCE(4, tp4)   TOK_REDUCE(5, tp5)   TOK_REDUCE(6, tp6)   TOK_REDUCE(7, tp7)
    TOK_REDUCE(8, tp8)   TOK_REDUCE(9, tp9)   TOK_REDUCE(10, tp10) TOK_REDUCE(11, tp11)
    TOK_REDUCE(12, tp12) TOK_REDUCE(13, tp13) TOK_REDUCE(14, tp14) TOK_REDUCE(15, tp15)
#undef TOK_REDUCE
}

// ---------------------------------------------------------------------------
// Problem pooling: 256 blocks (1 problem each), 256 threads.
// ---------------------------------------------------------------------------
__global__ __launch_bounds__(256)
void pool_problem(const float* __restrict__ attnL, const __hip_bfloat16* __restrict__ vals,
                  const int* __restrict__ labels,
                  const float* __restrict__ W_final, const float* __restrict__ b_final,
                  float* __restrict__ out_logits, float* __restrict__ out_labels) {
    __shared__ float w_lds[512 * 4];
    __shared__ float wred[4][4];
    __shared__ float psum[4];
    __shared__ int   lred[4];

    int p = blockIdx.x;
    int t = threadIdx.x;
    int lane = t & 63, wid = t >> 6;
    const float* abase = attnL + (size_t)p * 512 * 4;

    f32x4 v0 = *reinterpret_cast<const f32x4*>(abase + (size_t)t * 4);
    f32x4 v1 = *reinterpret_cast<const f32x4*>(abase + (size_t)(t + 256) * 4);

    float mh[4];
#pragma unroll
    for (int h = 0; h < 4; h++) mh[h] = fmaxf(v0[h], v1[h]);
#pragma unroll
    for (int h = 0; h < 4; h++)
        for (int mask = 1; mask < 64; mask <<= 1) mh[h] = fmaxf(mh[h], __shfl_xor(mh[h], mask));
    if (lane == 0) {
#pragma unroll
        for (int h = 0; h < 4; h++) wred[wid][h] = mh[h];
    }
    __syncthreads();
#pragma unroll
    for (int h = 0; h < 4; h++)
        mh[h] = fmaxf(fmaxf(wred[0][h], wred[1][h]), fmaxf(wred[2][h], wred[3][h]));
    __syncthreads();

    float Zh[4];
    f32x4 e0, e1;
#pragma unroll
    for (int h = 0; h < 4; h++) {
        e0[h] = __expf(v0[h] - mh[h]);
        e1[h] = __expf(v1[h] - mh[h]);
        Zh[h] = e0[h] + e1[h];
    }
    *reinterpret_cast<f32x4*>(&w_lds[t * 4]) = e0;
    *reinterpret_cast<f32x4*>(&w_lds[(t + 256) * 4]) = e1;
#pragma unroll
    for (int h = 0; h < 4; h++)
        for (int mask = 1; mask < 64; mask <<= 1) Zh[h] += __shfl_xor(Zh[h], mask);
    if (lane == 0) {
#pragma unroll
        for (int h = 0; h < 4; h++) wred[wid][h] = Zh[h];
    }
    __syncthreads();
#pragma unroll
    for (int h = 0; h < 4; h++) Zh[h] = wred[0][h] + wred[1][h] + wred[2][h] + wred[3][h];

    int h = t >> 6;
    const __hip_bfloat16* col = vals + (size_t)p * 512 * 256 + t;
    float pooled = 0.f;
#pragma unroll 8
    for (int s = 0; s < 512; s++)
        pooled += w_lds[s * 4 + h] * __bfloat162float(col[(size_t)s * 256]);
    float part = (pooled / Zh[h]) * W_final[t];
    for (int mask = 1; mask < 64; mask <<= 1) part += __shfl_xor(part, mask);
    if (lane == 0) psum[wid] = part;

    int lmin = min(labels[p * 512 + t], labels[p * 512 + t + 256]);
    for (int mask = 1; mask < 64; mask <<= 1) lmin = min(lmin, __shfl_xor(lmin, mask));
    if (lane == 0) lred[wid] = lmin;
    __syncthreads();
    if (t == 0) {
        out_logits[p] = psum[0] + psum[1] + psum[2] + psum[3] + b_final[0];
        out_labels[p] = (float)min(min(lred[0], lred[1]), min(lred[2], lred[3]));
    }
}

// ---------------------------------------------------------------------------
// Line pooling: one wave per line (16 tokens). Grid 2048 x 256 threads.
// ---------------------------------------------------------------------------
__global__ __launch_bounds__(256)
void pool_line(const float* __restrict__ attnL, const __hip_bfloat16* __restrict__ vals,
               const int* __restrict__ labels,
               const float* __restrict__ W_final, const float* __restrict__ b_final,
               float* __restrict__ out_logits, float* __restrict__ out_labels) {
    int wid = threadIdx.x >> 6, lane = threadIdx.x & 63;
    int line = blockIdx.x * 4 + wid;

    float x = attnL[(size_t)line * 64 + lane];
    float mm = x;
    mm = fmaxf(mm, __shfl_xor(mm, 4));
    mm = fmaxf(mm, __shfl_xor(mm, 8));
    mm = fmaxf(mm, __shfl_xor(mm, 16));
    mm = fmaxf(mm, __shfl_xor(mm, 32));
    float e = __expf(x - mm);
    float Z = e;
    Z += __shfl_xor(Z, 4);
    Z += __shfl_xor(Z, 8);
    Z += __shfl_xor(Z, 16);
    Z += __shfl_xor(Z, 32);
    float w = e / Z;

    const __hip_bfloat16* vbase = vals + (size_t)line * 16 * 256;
    float logit_part = 0.f;
#pragma unroll
    for (int j = 0; j < 4; j++) {
        float pooled = 0.f;
#pragma unroll
        for (int s = 0; s < 16; s++) {
            float ws = __shfl(w, s * 4 + j);
            pooled += ws * __bfloat162float(vbase[(size_t)s * 256 + j * 64 + lane]);
        }
        logit_part += pooled * W_final[j * 64 + lane];
    }
    for (int mask = 1; mask < 64; mask <<= 1) logit_part += __shfl_xor(logit_part, mask);

    int lab = (lane < 16) ? labels[line * 16 + lane] : 0x7fffffff;
    for (int mask = 1; mask < 64; mask <<= 1) lab = min(lab, __shfl_xor(lab, mask));

    if (lane == 0) {
        out_logits[line] = logit_part + b_final[0];
        out_labels[line] = (float)lab;
    }
}

// ---------------------------------------------------------------------------
extern "C" void kernel_launch(void* const* d_in, const int* in_sizes, int n_in,
                              void* d_out, int out_size, void* d_ws, size_t ws_size,
                              hipStream_t stream) {
    const float* emb     = (const float*)d_in[0];
    const float* W_down  = (const float*)d_in[1];
    const float* b_down  = (const float*)d_in[2];
    const float* W_final = (const float*)d_in[3];
    const float* b_final = (const float*)d_in[4];
    const int*   labels  = (const int*)d_in[5];

    float* out      = (float*)d_out;
    float* tok      = out;               // [131072]
    float* line_lg  = out + 131072;      // [8192]
    float* line_lb  = out + 139264;      // [8192]
    float* prob_lg  = out + 147456;      // [256]
    float* prob_lb  = out + 147712;      // [256]

    __hip_bfloat16* Wfrag = (__hip_bfloat16*)d_ws;                      // 1.2 MB
    float* attnL = (float*)((char*)d_ws + ((size_t)4 << 20));           // 2.1 MB
    __hip_bfloat16* vals = (__hip_bfloat16*)((char*)d_ws + ((size_t)8 << 20)); // 67 MB

    prep_wfrag<<<KS16 * NF32, 64, 0, stream>>>(W_down, Wfrag);
    gemm_act<<<T_TOK / 128, 256, 0, stream>>>(emb, Wfrag, b_down, W_final, b_final,
                                              attnL, vals, tok);
    pool_problem<<<256, 256, 0, stream>>>(attnL, vals, labels, W_final, b_final, prob_lg, prob_lb);
    pool_line<<<2048, 256, 0, stream>>>(attnL, vals, labels, W_final, b_final, line_lg, line_lb);
}